// Round 8
// baseline (3930.377 us; speedup 1.0000x reference)
//
#include <hip/hip_runtime.h>
#include <math.h>

#define TS 64
#define NN 2048
#define NE 32768
#define NH 6
#define NB 128   // 2*TS graph instances
#define BCAP 6144  // bucket capacity per (graph, dst-range); avg 4096, sd~60

typedef __attribute__((ext_vector_type(8))) __bf16 bf16x8;
typedef __attribute__((ext_vector_type(4))) float f32x4;

__device__ __forceinline__ float lrelu(float x){ return x >= 0.0f ? x : 0.2f*x; }
__device__ __forceinline__ float eluf(float x){ return x > 0.0f ? x : expm1f(x); }
__device__ __forceinline__ float sigm(float x){ return 1.0f/(1.0f+expf(-x)); }
__device__ __forceinline__ unsigned short bfhi(float x){ return (unsigned short)(__float_as_uint(x) >> 16); }
__device__ __forceinline__ float bff(unsigned short u){ return __uint_as_float(((unsigned int)u) << 16); }
__device__ __forceinline__ unsigned int packf(float v){
  unsigned short h = bfhi(v);
  unsigned short l = bfhi(v - bff(h));
  return (unsigned int)h | ((unsigned int)l << 16);
}

struct PrepArgs {
  const float* W[4];
  const float* aS[4];
  const float* aD[4];
};

// ---------- all-layer prep: uS,uD [H*FIN]; B split+transposed bf16 hi/lo [N][K] ----------
__global__ void prep_all_kernel(PrepArgs pa, float* __restrict__ uS, float* __restrict__ uD,
                                unsigned short* __restrict__ bth,
                                unsigned short* __restrict__ btl) {
  const int FINs[4]  = {4, 128, 128, 64};
  const int FOUTs[4] = {128, 128, 64, 64};
  const int uoffs[4] = {0, 24, 792, 1560};
  const int woffs[4] = {0, 3072, 101376, 150528};
  int l = blockIdx.y;
  int FIN = FINs[l], FOUT = FOUTs[l], K = NH * FIN;
  const float* W = pa.W[l];
  int idx = blockIdx.x * 256 + threadIdx.x;
  if (idx < K * FOUT) {
    int k = idx / FOUT, o = idx - k * FOUT;
    int h = k / FIN, f = k - h * FIN;
    float v = W[(size_t)(f * NH + h) * FOUT + o] * (1.0f / NH);
    unsigned short hb = bfhi(v);
    unsigned short lb = bfhi(v - bff(hb));
    bth[woffs[l] + (size_t)o * K + k] = hb;
    btl[woffs[l] + (size_t)o * K + k] = lb;
  }
  if (idx < NH * FIN) {
    int h = idx / FIN, f = idx - h * FIN;
    const float* wr = W + (size_t)(f * NH + h) * FOUT;
    const float* as = pa.aS[l] + h * FOUT;
    const float* ad = pa.aD[l] + h * FOUT;
    float ss = 0.f, dd = 0.f;
    for (int o = 0; o < FOUT; ++o) { float w = wr[o]; ss += w * as[o]; dd += w * ad[o]; }
    uS[uoffs[l] + idx] = ss;
    uD[uoffs[l] + idx] = dd;
  }
}

// ---------- CSR step 1: partial histograms (8 blocks/graph) ----------
__global__ __launch_bounds__(256)
void hist_part_kernel(const int* __restrict__ ei1, const int* __restrict__ ei2,
                      int* __restrict__ deg) {
  __shared__ int cnt[NN];
  int blk = blockIdx.x, t = threadIdx.x;
  int g = blk & (NB - 1), c = blk >> 7;
  int tt = g >> 1, s = g & 1;
  const int* dstp = (s ? ei2 : ei1) + (size_t)(tt * 2 + 1) * NE;
  for (int i = t; i < NN; i += 256) cnt[i] = 0;
  __syncthreads();
  int e0 = c * 4096;
  for (int i = t; i < 4096; i += 256) atomicAdd(&cnt[dstp[e0 + i]], 1);
  __syncthreads();
  for (int i = t; i < NN; i += 256) { int v = cnt[i]; if (v) atomicAdd(&deg[(size_t)g * NN + i], v); }
}

// ---------- CSR step 2: per-graph exclusive scan ----------
__global__ __launch_bounds__(256)
void scan_kernel(const int* __restrict__ deg, int* __restrict__ row_ptr) {
  __shared__ int part[256];
  int g = blockIdx.x, t = threadIdx.x;
  const int* dg = deg + (size_t)g * NN;
  int loc[8]; int run = 0;
  for (int i = 0; i < 8; ++i) { loc[i] = run; run += dg[t * 8 + i]; }
  part[t] = run;
  __syncthreads();
  if (t == 0) { int acc = 0; for (int i = 0; i < 256; ++i) { int v = part[i]; part[i] = acc; acc += v; } }
  __syncthreads();
  int o = part[t];
  int* rp = row_ptr + (size_t)g * (NN + 1);
  for (int i = 0; i < 8; ++i) rp[t * 8 + i] = o + loc[i];
  if (t == 255) rp[NN] = o + run;
}

// ---------- CSR step 3: bucket edges by dst-range, coalesced appends ----------
__global__ __launch_bounds__(256)
void bucketA_kernel(const int* __restrict__ ei1, const int* __restrict__ ei2,
                    const float* __restrict__ ew1, const float* __restrict__ ew2,
                    int* __restrict__ bktCnt, int2* __restrict__ bkt) {
  __shared__ int cnt8[8], base8[8], cur8[8];
  int blk = blockIdx.x, t = threadIdx.x;
  int g = blk & (NB - 1), c = blk >> 7;
  int tt = g >> 1, s = g & 1;
  const int* ei = s ? ei2 : ei1;
  const int* srcp = ei + (size_t)(tt * 2) * NE;
  const int* dstp = ei + (size_t)(tt * 2 + 1) * NE;
  const float* ewp = (s ? ew2 : ew1) + (size_t)tt * NE;
  if (t < 8) cnt8[t] = 0;
  __syncthreads();
  int e0 = c * 4096;
  for (int i = t; i < 4096; i += 256) atomicAdd(&cnt8[dstp[e0 + i] >> 8], 1);
  __syncthreads();
  if (t < 8) { base8[t] = atomicAdd(&bktCnt[g * 8 + t], cnt8[t]); cur8[t] = 0; }
  __syncthreads();
  for (int i = t; i < 4096; i += 256) {
    int e = e0 + i;
    int d = dstp[e];
    int r = d >> 8;
    int pos = base8[r] + atomicAdd(&cur8[r], 1);
    bkt[((size_t)g * 8 + r) * BCAP + pos] =
        make_int2(srcp[e] | ((d & 255) << 16), __float_as_int(ewp[e]));
  }
}

// ---------- CSR step 4: within-bucket scatter (sequential read, windowed write) ----------
__global__ __launch_bounds__(256)
void scatterB_kernel(const int* __restrict__ bktCnt, const int2* __restrict__ bkt,
                     const int* __restrict__ row_ptr, int2* __restrict__ edges) {
  __shared__ int cur[256];
  int blk = blockIdx.x, t = threadIdx.x;
  int g = blk & (NB - 1), r = blk >> 7;
  cur[t] = row_ptr[(size_t)g * (NN + 1) + r * 256 + t];
  __syncthreads();
  int n = bktCnt[g * 8 + r];
  const int2* bp = bkt + ((size_t)g * 8 + r) * BCAP;
  int2* ed = edges + (size_t)g * NE;
  for (int e = t; e < n; e += 256) {
    int2 v = bp[e];
    int dr = v.x >> 16;
    int src = v.x & 0xffff;
    int pos = atomicAdd(&cur[dr], 1);
    ed[pos] = make_int2(src, v.y);
  }
}

// ---------- stage x into xbuf + layer-0 s/d logits ----------
__global__ __launch_bounds__(256)
void copyx_sd0_kernel(const float* __restrict__ x1, const float* __restrict__ x2,
                      const float* __restrict__ uS0, const float* __restrict__ uD0,
                      float* __restrict__ xbuf, float* __restrict__ sdv, int c0) {
  __shared__ float uL[48];
  int t = threadIdx.x;
  if (t < 24) uL[t] = uS0[t];
  else if (t < 48) uL[t] = uD0[t - 24];
  __syncthreads();
  int nodeg = blockIdx.x * 256 + t;
  int gl = nodeg >> 11, n = nodeg & (NN - 1);
  int gi = c0 + gl;
  int tt = gi >> 1, s = gi & 1;
  const float* x = s ? x2 : x1;
  float4 xv = *(const float4*)(x + ((size_t)tt * NN + n) * 4);
  *(float4*)(xbuf + (size_t)nodeg * 4) = xv;
  float* sd = sdv + (size_t)nodeg * 12;
  #pragma unroll
  for (int j = 0; j < 12; ++j) {
    const float* u = uL + (j < 6 ? j * 4 : 24 + (j - 6) * 4);
    sd[j] = xv.x * u[0] + xv.y * u[1] + xv.z * u[2] + xv.w * u[3];
  }
}

// ---------- FUSED layer-0: softmax+aggregate (FIN=4) into MFMA staging + GEMM (K=24) ----------
__global__ __launch_bounds__(256)
void gemm0f_kernel(const float* __restrict__ hx, const float* __restrict__ sdv,
                   const int* __restrict__ row_ptr, const int2* __restrict__ edges,
                   const unsigned short* __restrict__ Bth, const unsigned short* __restrict__ Btl,
                   const float* __restrict__ bias, float* __restrict__ C,
                   int sw, const float* __restrict__ uSn, const float* __restrict__ uDn,
                   float* __restrict__ sdo, int c0) {
  constexpr int BN = 128, K = 24;
  constexpr int STG_B = (2048 + 2048 + BN * 32 + BN * 32) * 2;
  constexpr int EPI_B = (64 * (BN + 1) + 12 * (BN + 1)) * 4;
  constexpr int SMEM_B = STG_B > EPI_B ? STG_B : EPI_B;
  __shared__ __align__(16) char smem[SMEM_B];
  __shared__ float mLs[64 * 6];
  unsigned short* AhL = (unsigned short*)smem;
  unsigned short* AlL = AhL + 2048;
  unsigned short* BhL = AlL + 2048;
  unsigned short* BlL = BhL + BN * 32;
  float* CT = (float*)smem;
  float* uL = CT + 64 * (BN + 1);
  int t = threadIdx.x;
  int lane = t & 63, wv = t >> 6;
  int wm = wv & 1, wc = wv >> 1;
  int l15 = lane & 15, lq = lane >> 4;
  int blk = blockIdx.x;
  const int BPG = NN / 64;
  int m0;
  if (sw) { int xcd = blk & 7, q = blk >> 3; int glx = xcd + ((q / BPG) << 3); int nb = q % BPG; m0 = glx * NN + nb * 64; }
  else    m0 = blk * 64;
  int gl = m0 >> 11, n0 = m0 & (NN - 1);
  int gi = c0 + gl;
  const int* rpg = row_ptr + (size_t)gi * (NN + 1);
  const int2* eg = edges + (size_t)gi * NE;
  const float* sdg = sdv + (size_t)gl * NN * 12;
  const float* hb = hx + (size_t)gl * NN * 4;

  for (int pid = t; pid < 64 * 6; pid += 256) {
    int nl = pid / 6, j = pid - nl * 6;
    int n = n0 + nl;
    int rp = rpg[n], re = rpg[n + 1];
    float d = sdg[n * 12 + 6 + j];
    float m = -INFINITY;
    for (int e = rp; e < re; ++e) m = fmaxf(m, lrelu(sdg[eg[e].x * 12 + j] + d));
    mLs[pid] = m;
  }
  __syncthreads();
  {
    int nl = t >> 2, f = t & 3;
    int n = n0 + nl;
    int rp = rpg[n], re = rpg[n + 1];
    float dj[6], mj[6];
    #pragma unroll
    for (int j = 0; j < 6; ++j) { dj[j] = sdg[n * 12 + 6 + j]; mj[j] = mLs[nl * 6 + j]; }
    float accv[6] = {0.f,0.f,0.f,0.f,0.f,0.f};
    float den[6]  = {0.f,0.f,0.f,0.f,0.f,0.f};
    for (int e = rp; e < re; ++e) {
      int2 p = eg[e];
      float wh = __int_as_float(p.y) * hb[(size_t)p.x * 4 + f];
      const float* srow = sdg + (size_t)p.x * 12;
      #pragma unroll
      for (int j = 0; j < 6; ++j) {
        float ex = expf(lrelu(srow[j] + dj[j]) - mj[j]);
        den[j] += ex;
        accv[j] += ex * wh;
      }
    }
    int s4 = (nl >> 1) & 3;
    #pragma unroll
    for (int j = 0; j < 6; ++j) {
      unsigned int u = packf(accv[j] / (den[j] + 1e-16f));
      int pos = nl * 32 + (((j >> 1) ^ s4) << 3) + ((j & 1) << 2) + f;
      AhL[pos] = (unsigned short)(u & 0xffff);
      AlL[pos] = (unsigned short)(u >> 16);
    }
    #pragma unroll
    for (int j = 6; j < 8; ++j) {
      int pos = nl * 32 + (((j >> 1) ^ s4) << 3) + ((j & 1) << 2) + f;
      AhL[pos] = 0; AlL[pos] = 0;
    }
  }
  #pragma unroll
  for (int i = 0; i < 2; ++i) {
    int q = t + i * 256;
    int n = q >> 2, c = q & 3;
    uint4 vh = make_uint4(0, 0, 0, 0), vl = make_uint4(0, 0, 0, 0);
    int k = c * 8;
    if (k < K) {
      vh = *(const uint4*)(Bth + (size_t)n * K + k);
      vl = *(const uint4*)(Btl + (size_t)n * K + k);
    }
    int pos = n * 32 + ((c ^ ((n >> 1) & 3)) << 3);
    *(uint4*)&BhL[pos] = vh;
    *(uint4*)&BlL[pos] = vl;
  }
  __syncthreads();
  f32x4 acc[2][4];
  #pragma unroll
  for (int i = 0; i < 2; ++i)
    #pragma unroll
    for (int j = 0; j < 4; ++j) { f32x4 z = {0.f,0.f,0.f,0.f}; acc[i][j] = z; }
  bf16x8 ah[2], al[2], bh[4], bl[4];
  #pragma unroll
  for (int fr = 0; fr < 2; ++fr) {
    int row = wm * 32 + fr * 16 + l15;
    int p = row * 32 + ((lq ^ ((row >> 1) & 3)) << 3);
    ah[fr] = *(const bf16x8*)&AhL[p];
    al[fr] = *(const bf16x8*)&AlL[p];
  }
  #pragma unroll
  for (int fc = 0; fc < 4; ++fc) {
    int row = wc * 64 + fc * 16 + l15;
    int p = row * 32 + ((lq ^ ((row >> 1) & 3)) << 3);
    bh[fc] = *(const bf16x8*)&BhL[p];
    bl[fc] = *(const bf16x8*)&BlL[p];
  }
  #pragma unroll
  for (int fr = 0; fr < 2; ++fr)
    #pragma unroll
    for (int fc = 0; fc < 4; ++fc) {
      acc[fr][fc] = __builtin_amdgcn_mfma_f32_16x16x32_bf16(ah[fr], bh[fc], acc[fr][fc], 0, 0, 0);
      acc[fr][fc] = __builtin_amdgcn_mfma_f32_16x16x32_bf16(ah[fr], bl[fc], acc[fr][fc], 0, 0, 0);
      acc[fr][fc] = __builtin_amdgcn_mfma_f32_16x16x32_bf16(al[fr], bh[fc], acc[fr][fc], 0, 0, 0);
    }
  __syncthreads();
  #pragma unroll
  for (int fr = 0; fr < 2; ++fr) {
    int rl0 = wm * 32 + fr * 16 + lq * 4;
    #pragma unroll
    for (int fc = 0; fc < 4; ++fc) {
      int col = wc * 64 + fc * 16 + l15;
      float bv = bias[col];
      #pragma unroll
      for (int r = 0; r < 4; ++r) {
        float v = eluf(acc[fr][fc][r] + bv);
        C[(size_t)(m0 + rl0 + r) * BN + col] = v;
        CT[(rl0 + r) * (BN + 1) + col] = v;
      }
    }
  }
  __syncthreads();
  for (int idx = t; idx < 12 * BN; idx += 256) {
    int j = idx / BN, f = idx - j * BN;
    uL[j * (BN + 1) + f] = (j < 6) ? uSn[j * BN + f] : uDn[(j - 6) * BN + f];
  }
  __syncthreads();
  for (int o = t; o < 64 * 12; o += 256) {
    int rl = o / 12, j = o - rl * 12;
    const float* ur = uL + j * (BN + 1);
    const float* cr = CT + rl * (BN + 1);
    float a = 0.f;
    for (int f = 0; f < BN; ++f) a += cr[f] * ur[f];
    sdo[(size_t)(m0 + rl) * 12 + j] = a;
  }
}

// ---------- FUSED layer (FIN=64/128): agg -> LDS A-tile -> MFMA GEMM + epilogue ----------
// EPI: 1 = ELU + write C (stride BN) + next-layer s/d logits; 2 = readout only
template<int FIN, int BN, int EPI>
__global__ __launch_bounds__(256)
void fused_layer_kernel(const float* __restrict__ h, const float* __restrict__ sdv,
                        const int* __restrict__ row_ptr, const int2* __restrict__ edges,
                        const unsigned short* __restrict__ Bth,
                        const unsigned short* __restrict__ Btl,
                        const float* __restrict__ bias, float* __restrict__ C,
                        int sw, const float* __restrict__ uSn, const float* __restrict__ uDn,
                        float* __restrict__ sdo,
                        const float* __restrict__ xn1, const float* __restrict__ xn2,
                        float* __restrict__ seqv, int c0) {
  constexpr int K = 6 * FIN;
  constexpr int BM = 32;
  constexpr int TPN = FIN / 4;           // float4 lanes per node
  constexpr int BPASS = 256 / TPN;       // nodes aggregated per pass
  constexpr int NBATCH = BM / BPASS;
  constexpr int CAP = 80;
  constexpr int PT = (BPASS * 6 >= 96) ? 2 : 4;
  constexpr int NF = BN / 32;            // col frags per wave (4 waves: 2 row x 2 col groups)
  constexpr int AGG_B = BPASS * CAP * 6 * 4 + BPASS * CAP * 4;
  constexpr int BSTG_B = BN * 32 * 2 * 2;
  constexpr int EPI1_B = (BM * (BN + 1) + 12 * (BN + 1)) * 4;
  constexpr int EPI2_B = BM * (BN + 1) * 4 + 64 * 4 + 256 * 4;
  constexpr int EPI_B = (EPI == 1) ? EPI1_B : EPI2_B;
  constexpr int U1 = AGG_B > BSTG_B ? AGG_B : BSTG_B;
  constexpr int U_B = U1 > EPI_B ? U1 : EPI_B;
  __shared__ __align__(16) unsigned short AhL[BM * K];
  __shared__ __align__(16) unsigned short AlL[BM * K];
  __shared__ __align__(16) char uni[U_B];
  __shared__ float mLs[BPASS * 6], ivLs[BPASS * 6];
  float* awL  = (float*)uni;                              // [BPASS][CAP][6]
  int*   srcL = (int*)(uni + BPASS * CAP * 6 * 4);        // [BPASS][CAP]
  unsigned short* BhL = (unsigned short*)uni;
  unsigned short* BlL = BhL + BN * 32;
  float* CT  = (float*)uni;                               // [BM][BN+1]
  float* uL  = CT + BM * (BN + 1);
  float* xnL = CT + BM * (BN + 1);
  float* red = xnL + 64;

  int t = threadIdx.x;
  int lane = t & 63, wv = t >> 6;
  int wm = wv & 1, wc = wv >> 1;
  int l15 = lane & 15, lq = lane >> 4;
  int blk = blockIdx.x;
  constexpr int BPG = NN / BM;           // 64 blocks per graph
  int m0;
  if (sw) { int xcd = blk & 7, q = blk >> 3; int glx = xcd + ((q / BPG) << 3); int nb = q % BPG; m0 = glx * NN + nb * BM; }
  else    m0 = blk * BM;
  int gl = m0 >> 11, n0 = m0 & (NN - 1);
  int gi = c0 + gl;
  const int* rpg = row_ptr + (size_t)gi * (NN + 1);
  const int2* eg = edges + (size_t)gi * NE;
  const float* sdg = sdv + (size_t)gl * NN * 12;
  const float4* hb4 = (const float4*)(h + (size_t)gl * NN * FIN);

  // ===== phase A: aggregate BM nodes into LDS A-tile (packed bf16 hi/lo, swizzled) =====
  for (int it = 0; it < NBATCH; ++it) {
    __syncthreads();
    int nb0 = n0 + it * BPASS;
    int pid = t / PT, sub = t % PT;
    if (pid < BPASS * 6) {
      int nl = pid / 6, j = pid - nl * 6;
      int n = nb0 + nl;
      int rp = rpg[n], re = rpg[n + 1];
      float d = sdg[n * 12 + 6 + j];
      float m = -INFINITY;
      for (int e = rp + sub; e < re; e += PT) m = fmaxf(m, lrelu(sdg[eg[e].x * 12 + j] + d));
      #pragma unroll
      for (int msk = PT >> 1; msk; msk >>= 1) m = fmaxf(m, __shfl_xor(m, msk, PT));
      float den = 0.f;
      for (int e = rp + sub; e < re; e += PT) {
        int2 p = eg[e];
        float ex = expf(lrelu(sdg[p.x * 12 + j] + d) - m);
        den += ex;
        int idx = e - rp;
        if (idx < CAP) {
          awL[(nl * CAP + idx) * 6 + j] = ex * __int_as_float(p.y);
          if (j == 0) srcL[nl * CAP + idx] = p.x;
        }
      }
      #pragma unroll
      for (int msk = PT >> 1; msk; msk >>= 1) den += __shfl_xor(den, msk, PT);
      if (sub == 0) { mLs[pid] = m; ivLs[pid] = 1.f / (den + 1e-16f); }
    }
    __syncthreads();
    int nl = t / TPN, f4 = t % TPN;
    int n = nb0 + nl;
    int row = it * BPASS + nl;
    int rp = rpg[n], re = rpg[n + 1];
    float4 acc6[6];
    #pragma unroll
    for (int j = 0; j < 6; ++j) acc6[j] = make_float4(0.f, 0.f, 0.f, 0.f);
    if (re - rp <= CAP) {
      for (int e = rp; e < re; ++e) {
        int idx = e - rp;
        int sct = srcL[nl * CAP + idx];
        float4 hv = hb4[(size_t)sct * TPN + f4];
        #pragma unroll
        for (int j = 0; j < 6; ++j) {
          float a = awL[(nl * CAP + idx) * 6 + j];
          acc6[j].x += a * hv.x; acc6[j].y += a * hv.y;
          acc6[j].z += a * hv.z; acc6[j].w += a * hv.w;
        }
      }
    } else {
      float dj[6], mj[6];
      #pragma unroll
      for (int j = 0; j < 6; ++j) { dj[j] = sdg[n * 12 + 6 + j]; mj[j] = mLs[nl * 6 + j]; }
      for (int e = rp; e < re; ++e) {
        int idx = e - rp;
        int2 p = eg[e];
        float4 hv = hb4[(size_t)p.x * TPN + f4];
        if (idx < CAP) {
          #pragma unroll
          for (int j = 0; j < 6; ++j) {
            float a = awL[(nl * CAP + idx) * 6 + j];
            acc6[j].x += a * hv.x; acc6[j].y += a * hv.y;
            acc6[j].z += a * hv.z; acc6[j].w += a * hv.w;
          }
        } else {
          float w = __int_as_float(p.y);
          const float* srow = sdg + (size_t)p.x * 12;
          #pragma unroll
          for (int j = 0; j < 6; ++j) {
            float a = expf(lrelu(srow[j] + dj[j]) - mj[j]) * w;
            acc6[j].x += a * hv.x; acc6[j].y += a * hv.y;
            acc6[j].z += a * hv.z; acc6[j].w += a * hv.w;
          }
        }
      }
    }
    int s4 = (row >> 1) & 3;
    #pragma unroll
    for (int j = 0; j < 6; ++j) {
      float iv = ivLs[nl * 6 + j];
      unsigned int ux = packf(acc6[j].x * iv), uy = packf(acc6[j].y * iv);
      unsigned int uz = packf(acc6[j].z * iv), uw = packf(acc6[j].w * iv);
      int k = j * FIN + f4 * 4;
      int r32 = k & 31;
      int pos = row * K + (k & ~31) + ((((r32 >> 3) ^ s4)) << 3) + (r32 & 7);
      *(ushort4*)&AhL[pos] = make_ushort4(ux & 0xffff, uy & 0xffff, uz & 0xffff, uw & 0xffff);
      *(ushort4*)&AlL[pos] = make_ushort4(ux >> 16, uy >> 16, uz >> 16, uw >> 16);
    }
  }

  // ===== phase B: GEMM, A from LDS, B staged per k-tile =====
  f32x4 accf[NF];
  #pragma unroll
  for (int j = 0; j < NF; ++j) { f32x4 z = {0.f, 0.f, 0.f, 0.f}; accf[j] = z; }
  for (int k0 = 0; k0 < K; k0 += 32) {
    __syncthreads();
    #pragma unroll
    for (int i = 0; i < BN / 64; ++i) {
      int q = t + i * 256;
      int n = q >> 2, c = q & 3;
      uint4 vh = *(const uint4*)(Bth + (size_t)n * K + k0 + c * 8);
      uint4 vl = *(const uint4*)(Btl + (size_t)n * K + k0 + c * 8);
      int pos = n * 32 + ((c ^ ((n >> 1) & 3)) << 3);
      *(uint4*)&BhL[pos] = vh;
      *(uint4*)&BlL[pos] = vl;
    }
    __syncthreads();
    int arow = wm * 16 + l15;
    int ap = arow * K + k0 + ((lq ^ ((arow >> 1) & 3)) << 3);
    bf16x8 ah = *(const bf16x8*)&AhL[ap];
    bf16x8 al_ = *(const bf16x8*)&AlL[ap];
    bf16x8 bh[NF], bl[NF];
    #pragma unroll
    for (int fc = 0; fc < NF; ++fc) {
      int brow = wc * (NF * 16) + fc * 16 + l15;
      int bp = brow * 32 + ((lq ^ ((brow >> 1) & 3)) << 3);
      bh[fc] = *(const bf16x8*)&BhL[bp];
      bl[fc] = *(const bf16x8*)&BlL[bp];
    }
    #pragma unroll
    for (int fc = 0; fc < NF; ++fc) {
      accf[fc] = __builtin_amdgcn_mfma_f32_16x16x32_bf16(ah, bh[fc], accf[fc], 0, 0, 0);
      accf[fc] = __builtin_amdgcn_mfma_f32_16x16x32_bf16(ah, bl[fc], accf[fc], 0, 0, 0);
      accf[fc] = __builtin_amdgcn_mfma_f32_16x16x32_bf16(al_, bh[fc], accf[fc], 0, 0, 0);
    }
  }
  __syncthreads();
  int rl0 = wm * 16 + lq * 4;
  #pragma unroll
  for (int fc = 0; fc < NF; ++fc) {
    int col = wc * (NF * 16) + fc * 16 + l15;
    float bv = bias[col];
    #pragma unroll
    for (int r = 0; r < 4; ++r) {
      float v = accf[fc][r] + bv;
      if (EPI == 1) {
        v = eluf(v);
        C[(size_t)(m0 + rl0 + r) * BN + col] = v;
      }
      CT[(rl0 + r) * (BN + 1) + col] = v;
    }
  }
  __syncthreads();
  if (EPI == 1) {
    for (int idx = t; idx < 12 * BN; idx += 256) {
      int j = idx / BN, f = idx - j * BN;
      uL[j * (BN + 1) + f] = (j < 6) ? uSn[j * BN + f] : uDn[(j - 6) * BN + f];
    }
    __syncthreads();
    for (int o = t; o < BM * 12; o += 256) {
      int rl = o / 12, j = o - rl * 12;
      const float* ur = uL + j * (BN + 1);
      const float* cr = CT + rl * (BN + 1);
      float a = 0.f;
      for (int f = 0; f < BN; ++f) a += cr[f] * ur[f];
      sdo[(size_t)(m0 + rl) * 12 + j] = a;
    }
  } else {
    int tt = gi >> 1, ss = gi & 1;
    const float* xn = (ss ? xn2 : xn1) + (size_t)tt * NN;
    if (t < BM) xnL[t] = xn[n0 + t];
    __syncthreads();
    int d = t & 63, q4 = t >> 6;
    float a = 0.f;
    #pragma unroll
    for (int i = 0; i < 8; ++i)
      a += xnL[q4 * 8 + i] * CT[(q4 * 8 + i) * (BN + 1) + d];
    red[t] = a;
    __syncthreads();
    if (t < 64)
      atomicAdd(&seqv[tt * 128 + ss * 64 + t],
                red[t] + red[t + 64] + red[t + 128] + red[t + 192]);
  }
}

// ---------- GRU: parallel gi precompute ----------
__global__ __launch_bounds__(128)
void gi_kernel(const float* __restrict__ seq, const float* __restrict__ Wih,
               const float* __restrict__ bih, float* __restrict__ giAll) {
  int o = blockIdx.x * 128 + threadIdx.x;   // 48 blocks -> TS*96
  int tt = o / 96, j = o - tt * 96;
  const float4* wr = (const float4*)(Wih + (size_t)j * 128);
  const float4* xr = (const float4*)(seq + (size_t)tt * 128);
  float a = bih[j];
  #pragma unroll 8
  for (int k = 0; k < 32; ++k) {
    float4 w = wr[k], x = xr[k];
    a += w.x * x.x + w.y * x.y + w.z * x.z + w.w * x.w;
  }
  giAll[o] = a;
}

// ---------- GRU sequential + head (small, 1 block) ----------
__global__ __launch_bounds__(128)
void gru_seq_kernel(const float* __restrict__ giAll, const float* __restrict__ Whh,
                    const float* __restrict__ bhh, const float* __restrict__ Wc1,
                    const float* __restrict__ bc1, const float* __restrict__ Wc2,
                    const float* __restrict__ bc2, float* __restrict__ out) {
  __shared__ __align__(16) float WhhL[96 * 32];
  __shared__ __align__(16) float giL[TS * 96];
  __shared__ float rnnS[TS * 32];
  __shared__ float Wc1L[512], Wc2L[48], bc1L[16], bc2L[3], bhhL[96];
  __shared__ float ghs[96];
  __shared__ __align__(16) float hs[32];
  int t = threadIdx.x;
  for (int i = t; i < 96 * 32; i += 128) WhhL[i] = Whh[i];
  for (int i = t; i < TS * 96; i += 128) giL[i] = giAll[i];
  for (int i = t; i < 512; i += 128) Wc1L[i] = Wc1[i];
  if (t < 48) Wc2L[t] = Wc2[t];
  if (t < 96) bhhL[t] = bhh[t];
  if (t >= 96 && t < 112) bc1L[t - 96] = bc1[t - 96];
  if (t >= 112 && t < 115) bc2L[t - 112] = bc2[t - 112];
  if (t < 32) hs[t] = 0.f;
  __syncthreads();
  for (int tt = 0; tt < TS; ++tt) {
    if (t < 96) {
      const float4* wr = (const float4*)(WhhL + t * 32);
      const float4* hr = (const float4*)hs;
      float b = bhhL[t];
      #pragma unroll
      for (int k = 0; k < 8; ++k) {
        float4 w = wr[k], x = hr[k];
        b += w.x * x.x + w.y * x.y + w.z * x.z + w.w * x.w;
      }
      ghs[t] = b;
    }
    __syncthreads();
    if (t < 32) {
      const float* gi = giL + tt * 96;
      float r = sigm(gi[t] + ghs[t]);
      float z = sigm(gi[32 + t] + ghs[32 + t]);
      float nv = tanhf(gi[64 + t] + r * ghs[64 + t]);
      float h2 = (1.f - z) * nv + z * hs[t];
      hs[t] = h2;
      rnnS[tt * 32 + t] = h2;
    }
    __syncthreads();
  }
  for (int o = t; o < TS * 3; o += 128) {
    int tt = o / 3, c = o - tt * 3;
    float accv = bc2L[c];
    #pragma unroll
    for (int m = 0; m < 16; ++m) {
      float hv = bc1L[m];
      #pragma unroll
      for (int k = 0; k < 32; ++k) hv += rnnS[tt * 32 + k] * Wc1L[k * 16 + m];
      hv = fmaxf(hv, 0.f);
      accv += hv * Wc2L[m * 3 + c];
    }
    out[o] = accv;
  }
}

static inline size_t alignup(size_t x) { return (x + 255) & ~(size_t)255; }
static inline size_t maxsz(size_t a, size_t b) { return a > b ? a : b; }

extern "C" void kernel_launch(void* const* d_in, const int* in_sizes, int n_in,
                              void* d_out, int out_size, void* d_ws, size_t ws_size,
                              hipStream_t stream) {
  const float* x1  = (const float*)d_in[0];
  const float* x2  = (const float*)d_in[1];
  const int*   ei1 = (const int*)d_in[2];
  const int*   ei2 = (const int*)d_in[3];
  const float* ew1 = (const float*)d_in[4];
  const float* ew2 = (const float*)d_in[5];
  const float* xn1 = (const float*)d_in[6];
  const float* xn2 = (const float*)d_in[7];
  const float* Wih = (const float*)d_in[25];
  const float* Whh = (const float*)d_in[26];
  const float* bih = (const float*)d_in[27];
  const float* bhh = (const float*)d_in[28];
  const float* Wc1 = (const float*)d_in[29];
  const float* bc1 = (const float*)d_in[30];
  const float* Wc2 = (const float*)d_in[31];
  const float* bc2 = (const float*)d_in[32];
  float* out = (float*)d_out;

  const size_t uoffs[4] = {0, 24, 792, 1560};
  const size_t woffs[4] = {0, 3072, 101376, 150528};

  size_t off = 0;
  auto take = [&](size_t bytes) -> size_t { size_t o = off; off += alignup(bytes); return o; };
  size_t o_rowptr = take((size_t)NB * (NN + 1) * sizeof(int));
  size_t o_edges  = take((size_t)NB * NE * sizeof(int2));
  size_t o_uS     = take(1944 * sizeof(float));
  size_t o_uD     = take(1944 * sizeof(float));
  size_t o_bth    = take(175104 * sizeof(unsigned short));
  size_t o_btl    = take(175104 * sizeof(unsigned short));
  size_t o_seq    = take((size_t)TS * 128 * sizeof(float));
  size_t o_gi     = take((size_t)TS * 96 * sizeof(float));
  size_t persistent = off;

  const size_t BKT_BYTES = (size_t)NB * 8 * BCAP * sizeof(int2);          // 48 MB
  const size_t BKT_NEED  = BKT_BYTES + 4096 + (size_t)NB * NN * sizeof(int);

  // G capped at 16: 2 graphs/XCD keeps gather working set inside one L2
  int G = 8;
  const int cand[2] = {16, 8};
  size_t chunkT = 0;
  for (int ci = 0; ci < 2; ++ci) {
    int g = cand[ci];
    size_t ct = alignup((size_t)g * NN * 4 * sizeof(float))
              + 2 * alignup((size_t)g * NN * 128 * sizeof(float))
              + 2 * alignup((size_t)g * NN * 12 * sizeof(float));
    if (persistent + maxsz(ct, BKT_NEED) <= ws_size) { G = g; chunkT = ct; break; }
    chunkT = ct;
  }
  size_t o_big = take(maxsz(chunkT, BKT_NEED));
  size_t b = o_big;
  size_t o_x   = b; b += alignup((size_t)G * NN * 4 * sizeof(float));
  size_t o_hA  = b; b += alignup((size_t)G * NN * 128 * sizeof(float));
  size_t o_hB  = b; b += alignup((size_t)G * NN * 128 * sizeof(float));
  size_t o_sdA = b; b += alignup((size_t)G * NN * 12 * sizeof(float));
  size_t o_sdB = b;
  int sw = ((G & 7) == 0) ? 1 : 0;

  char* ws = (char*)d_ws;
  int*   row_ptr = (int*)(ws + o_rowptr);
  int2*  edges   = (int2*)(ws + o_edges);
  float* uS   = (float*)(ws + o_uS);
  float* uD   = (float*)(ws + o_uD);
  unsigned short* bth = (unsigned short*)(ws + o_bth);
  unsigned short* btl = (unsigned short*)(ws + o_btl);
  float* seq   = (float*)(ws + o_seq);
  float* giAll = (float*)(ws + o_gi);
  float* xbuf = (float*)(ws + o_x);
  float* hA   = (float*)(ws + o_hA);
  float* hB   = (float*)(ws + o_hB);
  float* sdA  = (float*)(ws + o_sdA);
  float* sdB  = (float*)(ws + o_sdB);
  // transient CSR scratch aliased onto the chunk region
  int2* bkt    = (int2*)(ws + o_big);
  int*  bktCnt = (int*)(ws + o_big + BKT_BYTES);
  int*  deg    = (int*)(ws + o_big + BKT_BYTES + 4096);

  // ---- prep + CSR + zero ----
  PrepArgs pa;
  for (int l = 0; l < 4; ++l) {
    pa.W[l]  = (const float*)d_in[9 + 4 * l];
    pa.aS[l] = (const float*)d_in[10 + 4 * l];
    pa.aD[l] = (const float*)d_in[11 + 4 * l];
  }
  prep_all_kernel<<<dim3(384, 4), 256, 0, stream>>>(pa, uS, uD, bth, btl);
  hipMemsetAsync(ws + o_big + BKT_BYTES, 0, 4096 + (size_t)NB * NN * sizeof(int), stream);
  hipMemsetAsync(seq, 0, (size_t)TS * 128 * sizeof(float), stream);
  hist_part_kernel<<<NB * 8, 256, 0, stream>>>(ei1, ei2, deg);
  scan_kernel<<<NB, 256, 0, stream>>>(deg, row_ptr);
  bucketA_kernel<<<NB * 8, 256, 0, stream>>>(ei1, ei2, ew1, ew2, bktCnt, bkt);
  scatterB_kernel<<<NB * 8, 256, 0, stream>>>(bktCnt, bkt, row_ptr, edges);

  // ---- chunked GAT pipeline (5 dispatches per chunk) ----
  for (int c0 = 0; c0 < NB; c0 += G) {
    int rows = G * NN;
    copyx_sd0_kernel<<<rows / 256, 256, 0, stream>>>(x1, x2, uS, uD, xbuf, sdA, c0);

    // layer 0: agg(FIN=4)+GEMM(K=24,BN=128) -> hA, sd -> sdB
    gemm0f_kernel<<<rows / 64, 256, 0, stream>>>(
        xbuf, sdA, row_ptr, edges, bth + woffs[0], btl + woffs[0],
        (const float*)d_in[12], hA, sw, uS + uoffs[1], uD + uoffs[1], sdB, c0);

    // layer 1: fused agg+GEMM (FIN=128 -> 128) -> hB, sd -> sdA
    fused_layer_kernel<128, 128, 1><<<rows / 32, 256, 0, stream>>>(
        hA, sdB, row_ptr, edges, bth + woffs[1], btl + woffs[1],
        (const float*)d_in[16], hB, sw, uS + uoffs[2], uD + uoffs[2], sdA,
        nullptr, nullptr, nullptr, c0);

    // layer 2: fused agg+GEMM (FIN=128 -> 64) -> hA (stride 64), sd -> sdB
    fused_layer_kernel<128, 64, 1><<<rows / 32, 256, 0, stream>>>(
        hB, sdA, row_ptr, edges, bth + woffs[2], btl + woffs[2],
        (const float*)d_in[20], hA, sw, uS + uoffs[3], uD + uoffs[3], sdB,
        nullptr, nullptr, nullptr, c0);

    // layer 3: fused agg+GEMM (FIN=64 -> 64), readout epilogue -> seq
    fused_layer_kernel<64, 64, 2><<<rows / 32, 256, 0, stream>>>(
        hA, sdB, row_ptr, edges, bth + woffs[3], btl + woffs[3],
        (const float*)d_in[24], nullptr, sw, nullptr, nullptr, nullptr,
        xn1, xn2, seq, c0);
  }

  // ---- GRU + head ----
  gi_kernel<<<48, 128, 0, stream>>>(seq, Wih, bih, giAll);
  gru_seq_kernel<<<1, 128, 0, stream>>>(giAll, Whh, bhh, Wc1, bc1, Wc2, bc2, out);
}

// Round 9
// 2625.606 us; speedup vs baseline: 1.4969x; 1.4969x over previous
//
#include <hip/hip_runtime.h>
#include <math.h>

#define TS 64
#define NN 2048
#define NE 32768
#define NH 6
#define NB 128   // 2*TS graph instances
#define BCAP 6144  // bucket capacity per (graph, dst-range); avg 4096, sd~60

typedef __attribute__((ext_vector_type(8))) __bf16 bf16x8;
typedef __attribute__((ext_vector_type(4))) float f32x4;

__device__ __forceinline__ float lrelu(float x){ return x >= 0.0f ? x : 0.2f*x; }
__device__ __forceinline__ float eluf(float x){ return x > 0.0f ? x : expm1f(x); }
__device__ __forceinline__ float sigm(float x){ return 1.0f/(1.0f+expf(-x)); }
__device__ __forceinline__ unsigned short bfhi(float x){ return (unsigned short)(__float_as_uint(x) >> 16); }
__device__ __forceinline__ float bff(unsigned short u){ return __uint_as_float(((unsigned int)u) << 16); }
__device__ __forceinline__ unsigned int packf(float v){
  unsigned short h = bfhi(v);
  unsigned short l = bfhi(v - bff(h));
  return (unsigned int)h | ((unsigned int)l << 16);
}

struct PrepArgs {
  const float* W[4];
  const float* aS[4];
  const float* aD[4];
};

// ---------- all-layer prep: uS,uD [H*FIN]; B split+transposed bf16 hi/lo [N][K] ----------
__global__ void prep_all_kernel(PrepArgs pa, float* __restrict__ uS, float* __restrict__ uD,
                                unsigned short* __restrict__ bth,
                                unsigned short* __restrict__ btl) {
  const int FINs[4]  = {4, 128, 128, 64};
  const int FOUTs[4] = {128, 128, 64, 64};
  const int uoffs[4] = {0, 24, 792, 1560};
  const int woffs[4] = {0, 3072, 101376, 150528};
  int l = blockIdx.y;
  int FIN = FINs[l], FOUT = FOUTs[l], K = NH * FIN;
  const float* W = pa.W[l];
  int idx = blockIdx.x * 256 + threadIdx.x;
  if (idx < K * FOUT) {
    int k = idx / FOUT, o = idx - k * FOUT;
    int h = k / FIN, f = k - h * FIN;
    float v = W[(size_t)(f * NH + h) * FOUT + o] * (1.0f / NH);
    unsigned short hb = bfhi(v);
    unsigned short lb = bfhi(v - bff(hb));
    bth[woffs[l] + (size_t)o * K + k] = hb;
    btl[woffs[l] + (size_t)o * K + k] = lb;
  }
  if (idx < NH * FIN) {
    int h = idx / FIN, f = idx - h * FIN;
    const float* wr = W + (size_t)(f * NH + h) * FOUT;
    const float* as = pa.aS[l] + h * FOUT;
    const float* ad = pa.aD[l] + h * FOUT;
    float ss = 0.f, dd = 0.f;
    for (int o = 0; o < FOUT; ++o) { float w = wr[o]; ss += w * as[o]; dd += w * ad[o]; }
    uS[uoffs[l] + idx] = ss;
    uD[uoffs[l] + idx] = dd;
  }
}

// ---------- CSR step 1: partial histograms (8 blocks/graph) ----------
__global__ __launch_bounds__(256)
void hist_part_kernel(const int* __restrict__ ei1, const int* __restrict__ ei2,
                      int* __restrict__ deg) {
  __shared__ int cnt[NN];
  int blk = blockIdx.x, t = threadIdx.x;
  int g = blk & (NB - 1), c = blk >> 7;
  int tt = g >> 1, s = g & 1;
  const int* dstp = (s ? ei2 : ei1) + (size_t)(tt * 2 + 1) * NE;
  for (int i = t; i < NN; i += 256) cnt[i] = 0;
  __syncthreads();
  int e0 = c * 4096;
  for (int i = t; i < 4096; i += 256) atomicAdd(&cnt[dstp[e0 + i]], 1);
  __syncthreads();
  for (int i = t; i < NN; i += 256) { int v = cnt[i]; if (v) atomicAdd(&deg[(size_t)g * NN + i], v); }
}

// ---------- CSR step 2: per-graph exclusive scan ----------
__global__ __launch_bounds__(256)
void scan_kernel(const int* __restrict__ deg, int* __restrict__ row_ptr) {
  __shared__ int part[256];
  int g = blockIdx.x, t = threadIdx.x;
  const int* dg = deg + (size_t)g * NN;
  int loc[8]; int run = 0;
  for (int i = 0; i < 8; ++i) { loc[i] = run; run += dg[t * 8 + i]; }
  part[t] = run;
  __syncthreads();
  if (t == 0) { int acc = 0; for (int i = 0; i < 256; ++i) { int v = part[i]; part[i] = acc; acc += v; } }
  __syncthreads();
  int o = part[t];
  int* rp = row_ptr + (size_t)g * (NN + 1);
  for (int i = 0; i < 8; ++i) rp[t * 8 + i] = o + loc[i];
  if (t == 255) rp[NN] = o + run;
}

// ---------- CSR step 3: bucket edges by dst-range, coalesced appends ----------
__global__ __launch_bounds__(256)
void bucketA_kernel(const int* __restrict__ ei1, const int* __restrict__ ei2,
                    const float* __restrict__ ew1, const float* __restrict__ ew2,
                    int* __restrict__ bktCnt, int2* __restrict__ bkt) {
  __shared__ int cnt8[8], base8[8], cur8[8];
  int blk = blockIdx.x, t = threadIdx.x;
  int g = blk & (NB - 1), c = blk >> 7;
  int tt = g >> 1, s = g & 1;
  const int* ei = s ? ei2 : ei1;
  const int* srcp = ei + (size_t)(tt * 2) * NE;
  const int* dstp = ei + (size_t)(tt * 2 + 1) * NE;
  const float* ewp = (s ? ew2 : ew1) + (size_t)tt * NE;
  if (t < 8) cnt8[t] = 0;
  __syncthreads();
  int e0 = c * 4096;
  for (int i = t; i < 4096; i += 256) atomicAdd(&cnt8[dstp[e0 + i] >> 8], 1);
  __syncthreads();
  if (t < 8) { base8[t] = atomicAdd(&bktCnt[g * 8 + t], cnt8[t]); cur8[t] = 0; }
  __syncthreads();
  for (int i = t; i < 4096; i += 256) {
    int e = e0 + i;
    int d = dstp[e];
    int r = d >> 8;
    int pos = base8[r] + atomicAdd(&cur8[r], 1);
    bkt[((size_t)g * 8 + r) * BCAP + pos] =
        make_int2(srcp[e] | ((d & 255) << 16), __float_as_int(ewp[e]));
  }
}

// ---------- CSR step 4: within-bucket scatter (sequential read, windowed write) ----------
__global__ __launch_bounds__(256)
void scatterB_kernel(const int* __restrict__ bktCnt, const int2* __restrict__ bkt,
                     const int* __restrict__ row_ptr, int2* __restrict__ edges) {
  __shared__ int cur[256];
  int blk = blockIdx.x, t = threadIdx.x;
  int g = blk & (NB - 1), r = blk >> 7;
  cur[t] = row_ptr[(size_t)g * (NN + 1) + r * 256 + t];
  __syncthreads();
  int n = bktCnt[g * 8 + r];
  const int2* bp = bkt + ((size_t)g * 8 + r) * BCAP;
  int2* ed = edges + (size_t)g * NE;
  for (int e = t; e < n; e += 256) {
    int2 v = bp[e];
    int dr = v.x >> 16;
    int src = v.x & 0xffff;
    int pos = atomicAdd(&cur[dr], 1);
    ed[pos] = make_int2(src, v.y);
  }
}

// ---------- layer-0 s/d logits for ALL graphs (once) ----------
__global__ __launch_bounds__(256)
void sd0_all_kernel(const float* __restrict__ x1, const float* __restrict__ x2,
                    const float* __restrict__ uS0, const float* __restrict__ uD0,
                    float* __restrict__ sd0) {
  __shared__ float uL[48];
  int t = threadIdx.x;
  if (t < 24) uL[t] = uS0[t];
  else if (t < 48) uL[t] = uD0[t - 24];
  __syncthreads();
  int nodeg = blockIdx.x * 256 + t;
  int gi = nodeg >> 11, n = nodeg & (NN - 1);
  int tt = gi >> 1, s = gi & 1;
  const float* x = s ? x2 : x1;
  float4 xv = *(const float4*)(x + ((size_t)tt * NN + n) * 4);
  float* sd = sd0 + (size_t)nodeg * 12;
  #pragma unroll
  for (int j = 0; j < 12; ++j) {
    const float* u = uL + (j < 6 ? j * 4 : 24 + (j - 6) * 4);
    sd[j] = xv.x * u[0] + xv.y * u[1] + xv.z * u[2] + xv.w * u[3];
  }
}

// ---------- FUSED layer-0: softmax+aggregate (FIN=4, x read direct) + GEMM (K=24) ----------
__global__ __launch_bounds__(256)
void gemm0f_kernel(const float* __restrict__ x1, const float* __restrict__ x2,
                   const float* __restrict__ sd0,
                   const int* __restrict__ row_ptr, const int2* __restrict__ edges,
                   const unsigned short* __restrict__ Bth, const unsigned short* __restrict__ Btl,
                   const float* __restrict__ bias, float* __restrict__ C,
                   int sw, const float* __restrict__ uSn, const float* __restrict__ uDn,
                   float* __restrict__ sdo, int c0) {
  constexpr int BN = 128, K = 24;
  constexpr int STG_B = (2048 + 2048 + BN * 32 + BN * 32) * 2;
  constexpr int EPI_B = (64 * (BN + 1) + 12 * (BN + 1)) * 4;
  constexpr int SMEM_B = STG_B > EPI_B ? STG_B : EPI_B;
  __shared__ __align__(16) char smem[SMEM_B];
  __shared__ float mLs[64 * 6];
  unsigned short* AhL = (unsigned short*)smem;
  unsigned short* AlL = AhL + 2048;
  unsigned short* BhL = AlL + 2048;
  unsigned short* BlL = BhL + BN * 32;
  float* CT = (float*)smem;
  float* uL = CT + 64 * (BN + 1);
  int t = threadIdx.x;
  int lane = t & 63, wv = t >> 6;
  int wm = wv & 1, wc = wv >> 1;
  int l15 = lane & 15, lq = lane >> 4;
  int blk = blockIdx.x;
  const int BPG = NN / 64;
  int m0;
  if (sw) { int xcd = blk & 7, q = blk >> 3; int glx = xcd + ((q / BPG) << 3); int nb = q % BPG; m0 = glx * NN + nb * 64; }
  else    m0 = blk * 64;
  int gl = m0 >> 11, n0 = m0 & (NN - 1);
  int gi = c0 + gl;
  int tt2 = gi >> 1, ss2 = gi & 1;
  const int* rpg = row_ptr + (size_t)gi * (NN + 1);
  const int2* eg = edges + (size_t)gi * NE;
  const float* sdg = sd0 + (size_t)gi * NN * 12;
  const float* hb = (ss2 ? x2 : x1) + (size_t)tt2 * NN * 4;

  for (int pid = t; pid < 64 * 6; pid += 256) {
    int nl = pid / 6, j = pid - nl * 6;
    int n = n0 + nl;
    int rp = rpg[n], re = rpg[n + 1];
    float d = sdg[n * 12 + 6 + j];
    float m = -INFINITY;
    for (int e = rp; e < re; ++e) m = fmaxf(m, lrelu(sdg[eg[e].x * 12 + j] + d));
    mLs[pid] = m;
  }
  __syncthreads();
  {
    int nl = t >> 2, f = t & 3;
    int n = n0 + nl;
    int rp = rpg[n], re = rpg[n + 1];
    float dj[6], mj[6];
    #pragma unroll
    for (int j = 0; j < 6; ++j) { dj[j] = sdg[n * 12 + 6 + j]; mj[j] = mLs[nl * 6 + j]; }
    float accv[6] = {0.f,0.f,0.f,0.f,0.f,0.f};
    float den[6]  = {0.f,0.f,0.f,0.f,0.f,0.f};
    for (int e = rp; e < re; ++e) {
      int2 p = eg[e];
      float wh = __int_as_float(p.y) * hb[(size_t)p.x * 4 + f];
      const float* srow = sdg + (size_t)p.x * 12;
      #pragma unroll
      for (int j = 0; j < 6; ++j) {
        float ex = expf(lrelu(srow[j] + dj[j]) - mj[j]);
        den[j] += ex;
        accv[j] += ex * wh;
      }
    }
    int s4 = (nl >> 1) & 3;
    #pragma unroll
    for (int j = 0; j < 6; ++j) {
      unsigned int u = packf(accv[j] / (den[j] + 1e-16f));
      int pos = nl * 32 + (((j >> 1) ^ s4) << 3) + ((j & 1) << 2) + f;
      AhL[pos] = (unsigned short)(u & 0xffff);
      AlL[pos] = (unsigned short)(u >> 16);
    }
    #pragma unroll
    for (int j = 6; j < 8; ++j) {
      int pos = nl * 32 + (((j >> 1) ^ s4) << 3) + ((j & 1) << 2) + f;
      AhL[pos] = 0; AlL[pos] = 0;
    }
  }
  #pragma unroll
  for (int i = 0; i < 2; ++i) {
    int q = t + i * 256;
    int n = q >> 2, c = q & 3;
    uint4 vh = make_uint4(0, 0, 0, 0), vl = make_uint4(0, 0, 0, 0);
    int k = c * 8;
    if (k < K) {
      vh = *(const uint4*)(Bth + (size_t)n * K + k);
      vl = *(const uint4*)(Btl + (size_t)n * K + k);
    }
    int pos = n * 32 + ((c ^ ((n >> 1) & 3)) << 3);
    *(uint4*)&BhL[pos] = vh;
    *(uint4*)&BlL[pos] = vl;
  }
  __syncthreads();
  f32x4 acc[2][4];
  #pragma unroll
  for (int i = 0; i < 2; ++i)
    #pragma unroll
    for (int j = 0; j < 4; ++j) { f32x4 z = {0.f,0.f,0.f,0.f}; acc[i][j] = z; }
  bf16x8 ah[2], al[2], bh[4], bl[4];
  #pragma unroll
  for (int fr = 0; fr < 2; ++fr) {
    int row = wm * 32 + fr * 16 + l15;
    int p = row * 32 + ((lq ^ ((row >> 1) & 3)) << 3);
    ah[fr] = *(const bf16x8*)&AhL[p];
    al[fr] = *(const bf16x8*)&AlL[p];
  }
  #pragma unroll
  for (int fc = 0; fc < 4; ++fc) {
    int row = wc * 64 + fc * 16 + l15;
    int p = row * 32 + ((lq ^ ((row >> 1) & 3)) << 3);
    bh[fc] = *(const bf16x8*)&BhL[p];
    bl[fc] = *(const bf16x8*)&BlL[p];
  }
  #pragma unroll
  for (int fr = 0; fr < 2; ++fr)
    #pragma unroll
    for (int fc = 0; fc < 4; ++fc) {
      acc[fr][fc] = __builtin_amdgcn_mfma_f32_16x16x32_bf16(ah[fr], bh[fc], acc[fr][fc], 0, 0, 0);
      acc[fr][fc] = __builtin_amdgcn_mfma_f32_16x16x32_bf16(ah[fr], bl[fc], acc[fr][fc], 0, 0, 0);
      acc[fr][fc] = __builtin_amdgcn_mfma_f32_16x16x32_bf16(al[fr], bh[fc], acc[fr][fc], 0, 0, 0);
    }
  __syncthreads();
  #pragma unroll
  for (int fr = 0; fr < 2; ++fr) {
    int rl0 = wm * 32 + fr * 16 + lq * 4;
    #pragma unroll
    for (int fc = 0; fc < 4; ++fc) {
      int col = wc * 64 + fc * 16 + l15;
      float bv = bias[col];
      #pragma unroll
      for (int r = 0; r < 4; ++r) {
        float v = eluf(acc[fr][fc][r] + bv);
        C[(size_t)(m0 + rl0 + r) * BN + col] = v;
        CT[(rl0 + r) * (BN + 1) + col] = v;
      }
    }
  }
  __syncthreads();
  for (int idx = t; idx < 12 * BN; idx += 256) {
    int j = idx / BN, f = idx - j * BN;
    uL[j * (BN + 1) + f] = (j < 6) ? uSn[j * BN + f] : uDn[(j - 6) * BN + f];
  }
  __syncthreads();
  for (int o = t; o < 64 * 12; o += 256) {
    int rl = o / 12, j = o - rl * 12;
    const float* ur = uL + j * (BN + 1);
    const float* cr = CT + rl * (BN + 1);
    float a = 0.f;
    for (int f = 0; f < BN; ++f) a += cr[f] * ur[f];
    sdo[(size_t)(m0 + rl) * 12 + j] = a;
  }
}

// ---------- softmax+aggregate (FIN=64/128): cached unnorm alpha, end-normalize ----------
template<int FIN, int PT>
__global__ __launch_bounds__(256)
void aggc_kernel(const float* __restrict__ h, const float* __restrict__ sdv,
                 const int* __restrict__ row_ptr, const int2* __restrict__ edges,
                 unsigned int* __restrict__ agg, int c0, int sw) {
  const int TPN = FIN / 4;
  const int NPB = 256 / TPN;
  const int IL = 4;
  const int BPG = NN / (NPB * IL);
  const int CAP = 80;
  __shared__ float awL[NPB][CAP][6];
  __shared__ int   srcL[NPB][CAP];
  __shared__ float mLs[NPB * 6], ivLs[NPB * 6];
  int t = threadIdx.x, blk = blockIdx.x;
  int gl, nb;
  if (sw) { int xcd = blk & 7, q = blk >> 3; gl = xcd + ((q / BPG) << 3); nb = q % BPG; }
  else    { gl = blk / BPG; nb = blk % BPG; }
  int gi = c0 + gl;
  const int* rpg = row_ptr + (size_t)gi * (NN + 1);
  const int2* eg = edges + (size_t)gi * NE;
  const float* sdg = sdv + (size_t)gl * NN * 12;
  const float4* hb4 = (const float4*)(h + (size_t)gl * NN * FIN);
  unsigned int* aggb = agg + (size_t)gl * NN * (6 * FIN);
  for (int it = 0; it < IL; ++it) {
    __syncthreads();
    int n0 = nb * (NPB * IL) + it * NPB;
    int pid = t / PT, sub = t % PT;
    if (pid < NPB * 6) {
      int nl = pid / 6, j = pid - nl * 6;
      int n = n0 + nl;
      int rp = rpg[n], re = rpg[n + 1];
      float d = sdg[n * 12 + 6 + j];
      float m = -INFINITY;
      for (int e = rp + sub; e < re; e += PT) m = fmaxf(m, lrelu(sdg[eg[e].x * 12 + j] + d));
      #pragma unroll
      for (int msk = PT >> 1; msk; msk >>= 1) m = fmaxf(m, __shfl_xor(m, msk, PT));
      float den = 0.f;
      for (int e = rp + sub; e < re; e += PT) {
        int2 p = eg[e];
        float ex = expf(lrelu(sdg[p.x * 12 + j] + d) - m);
        den += ex;
        int idx = e - rp;
        if (idx < CAP) {
          awL[nl][idx][j] = ex * __int_as_float(p.y);
          if (j == 0) srcL[nl][idx] = p.x;
        }
      }
      #pragma unroll
      for (int msk = PT >> 1; msk; msk >>= 1) den += __shfl_xor(den, msk, PT);
      if (sub == 0) { mLs[pid] = m; ivLs[pid] = 1.f / (den + 1e-16f); }
    }
    __syncthreads();
    int nl = t / TPN, f4 = t % TPN;
    int n = n0 + nl;
    int rp = rpg[n], re = rpg[n + 1];
    float4 acc[6];
    #pragma unroll
    for (int j = 0; j < 6; ++j) acc[j] = make_float4(0.f, 0.f, 0.f, 0.f);
    if (re - rp <= CAP) {
      for (int e = rp; e < re; ++e) {
        int idx = e - rp;
        int sct = srcL[nl][idx];
        float4 hv = hb4[(size_t)sct * TPN + f4];
        #pragma unroll
        for (int j = 0; j < 6; ++j) {
          float a = awL[nl][idx][j];
          acc[j].x += a * hv.x; acc[j].y += a * hv.y;
          acc[j].z += a * hv.z; acc[j].w += a * hv.w;
        }
      }
    } else {
      float dj[6], mj[6];
      #pragma unroll
      for (int j = 0; j < 6; ++j) { dj[j] = sdg[n * 12 + 6 + j]; mj[j] = mLs[nl * 6 + j]; }
      for (int e = rp; e < re; ++e) {
        int idx = e - rp;
        int2 p = eg[e];
        float4 hv = hb4[(size_t)p.x * TPN + f4];
        if (idx < CAP) {
          #pragma unroll
          for (int j = 0; j < 6; ++j) {
            float a = awL[nl][idx][j];
            acc[j].x += a * hv.x; acc[j].y += a * hv.y;
            acc[j].z += a * hv.z; acc[j].w += a * hv.w;
          }
        } else {
          float w = __int_as_float(p.y);
          const float* srow = sdg + (size_t)p.x * 12;
          #pragma unroll
          for (int j = 0; j < 6; ++j) {
            float a = expf(lrelu(srow[j] + dj[j]) - mj[j]) * w;
            acc[j].x += a * hv.x; acc[j].y += a * hv.y;
            acc[j].z += a * hv.z; acc[j].w += a * hv.w;
          }
        }
      }
    }
    unsigned int* ar = aggb + (size_t)n * (6 * FIN);
    #pragma unroll
    for (int j = 0; j < 6; ++j) {
      float iv = ivLs[nl * 6 + j];
      uint4 pk;
      pk.x = packf(acc[j].x * iv); pk.y = packf(acc[j].y * iv);
      pk.z = packf(acc[j].z * iv); pk.w = packf(acc[j].w * iv);
      *(uint4*)(ar + j * FIN + f4 * 4) = pk;
    }
  }
}

// ---------- MFMA GEMM (A pre-split packed bf16 hi|lo) + fused epilogue; LDS overlay ----------
// EPI: 1 = write C + next-layer s/d logits; 2 = readout only (no C write)
template<int BN, int MF, int NF, int WMC, int WCC, int EPI>
__global__ __launch_bounds__(256)
void gemm_mfma_kernel(const unsigned int* __restrict__ A,
                      const unsigned short* __restrict__ Bth,
                      const unsigned short* __restrict__ Btl,
                      const float* __restrict__ bias, float* __restrict__ C,
                      int K, int act, int sw,
                      const float* __restrict__ uSn, const float* __restrict__ uDn,
                      float* __restrict__ sdv,
                      const float* __restrict__ xn1, const float* __restrict__ xn2,
                      float* __restrict__ seqv, int c0) {
  static_assert(BN == WCC * NF * 16 && 64 == WMC * MF * 16, "tile mismatch");
  constexpr int STG_B = (2048 + 2048 + BN * 32 + BN * 32) * 2;
  constexpr int EPI_B = (64 * (BN + 1) + 12 * (BN + 1) + 64 + 256) * 4;
  constexpr int SMEM_B = STG_B > EPI_B ? STG_B : EPI_B;
  __shared__ __align__(16) char smem[SMEM_B];
  unsigned short* AhL = (unsigned short*)smem;
  unsigned short* AlL = AhL + 2048;
  unsigned short* BhL = AlL + 2048;
  unsigned short* BlL = BhL + BN * 32;
  float* CT  = (float*)smem;
  float* uL  = CT + 64 * (BN + 1);
  float* xnL = uL + 12 * (BN + 1);
  float* red = xnL + 64;
  int t = threadIdx.x;
  int lane = t & 63, wv = t >> 6;
  int wm = wv % WMC, wc = wv / WMC;
  int l15 = lane & 15, lq = lane >> 4;
  int blk = blockIdx.x;
  const int BPG = NN / 64;
  int m0;
  if (sw) { int xcd = blk & 7, q = blk >> 3; int gl = xcd + ((q / BPG) << 3); int nb = q % BPG; m0 = gl * NN + nb * 64; }
  else    m0 = blk * 64;
  f32x4 acc[MF][NF];
  #pragma unroll
  for (int i = 0; i < MF; ++i)
    #pragma unroll
    for (int j = 0; j < NF; ++j) { f32x4 z = {0.f, 0.f, 0.f, 0.f}; acc[i][j] = z; }

  for (int k0 = 0; k0 < K; k0 += 32) {
    __syncthreads();
    #pragma unroll
    for (int i = 0; i < 2; ++i) {
      int q = t + i * 256;
      int row = q >> 3, c4 = q & 7;
      uint4 av = make_uint4(0, 0, 0, 0);
      int k = k0 + c4 * 4;
      if (k < K) av = *(const uint4*)(A + (size_t)(m0 + row) * K + k);
      int pos = row * 32 + (((c4 >> 1) ^ ((row >> 1) & 3)) << 3) + ((c4 & 1) << 2);
      *(ushort4*)&AhL[pos] = make_ushort4(av.x & 0xffff, av.y & 0xffff, av.z & 0xffff, av.w & 0xffff);
      *(ushort4*)&AlL[pos] = make_ushort4(av.x >> 16, av.y >> 16, av.z >> 16, av.w >> 16);
    }
    #pragma unroll
    for (int i = 0; i < BN / 64; ++i) {
      int q = t + i * 256;
      int n = q >> 2, c = q & 3;
      uint4 vh = make_uint4(0, 0, 0, 0), vl = make_uint4(0, 0, 0, 0);
      int k = k0 + c * 8;
      if (k < K) {
        vh = *(const uint4*)(Bth + (size_t)n * K + k);
        vl = *(const uint4*)(Btl + (size_t)n * K + k);
      }
      int pos = n * 32 + ((c ^ ((n >> 1) & 3)) << 3);
      *(uint4*)&BhL[pos] = vh;
      *(uint4*)&BlL[pos] = vl;
    }
    __syncthreads();
    bf16x8 ah[MF], al[MF], bh[NF], bl[NF];
    #pragma unroll
    for (int fr = 0; fr < MF; ++fr) {
      int row = wm * MF * 16 + fr * 16 + l15;
      int p = row * 32 + ((lq ^ ((row >> 1) & 3)) << 3);
      ah[fr] = *(const bf16x8*)&AhL[p];
      al[fr] = *(const bf16x8*)&AlL[p];
    }
    #pragma unroll
    for (int fc = 0; fc < NF; ++fc) {
      int row = wc * NF * 16 + fc * 16 + l15;
      int p = row * 32 + ((lq ^ ((row >> 1) & 3)) << 3);
      bh[fc] = *(const bf16x8*)&BhL[p];
      bl[fc] = *(const bf16x8*)&BlL[p];
    }
    #pragma unroll
    for (int fr = 0; fr < MF; ++fr)
      #pragma unroll
      for (int fc = 0; fc < NF; ++fc) {
        acc[fr][fc] = __builtin_amdgcn_mfma_f32_16x16x32_bf16(ah[fr], bh[fc], acc[fr][fc], 0, 0, 0);
        acc[fr][fc] = __builtin_amdgcn_mfma_f32_16x16x32_bf16(ah[fr], bl[fc], acc[fr][fc], 0, 0, 0);
        acc[fr][fc] = __builtin_amdgcn_mfma_f32_16x16x32_bf16(al[fr], bh[fc], acc[fr][fc], 0, 0, 0);
      }
  }
  __syncthreads();
  #pragma unroll
  for (int fr = 0; fr < MF; ++fr) {
    int rl0 = wm * MF * 16 + fr * 16 + lq * 4;
    #pragma unroll
    for (int fc = 0; fc < NF; ++fc) {
      int col = wc * NF * 16 + fc * 16 + l15;
      float bv = bias[col];
      #pragma unroll
      for (int r = 0; r < 4; ++r) {
        float v = acc[fr][fc][r] + bv;
        if (act) v = eluf(v);
        if (EPI != 2) C[(size_t)(m0 + rl0 + r) * BN + col] = v;
        CT[(rl0 + r) * (BN + 1) + col] = v;
      }
    }
  }
  __syncthreads();
  if (EPI == 1) {
    for (int idx = t; idx < 12 * BN; idx += 256) {
      int j = idx / BN, f = idx - j * BN;
      uL[j * (BN + 1) + f] = (j < 6) ? uSn[j * BN + f] : uDn[(j - 6) * BN + f];
    }
    __syncthreads();
    for (int o = t; o < 64 * 12; o += 256) {
      int rl = o / 12, j = o - rl * 12;
      const float* ur = uL + j * (BN + 1);
      const float* cr = CT + rl * (BN + 1);
      float a = 0.f;
      for (int f = 0; f < BN; ++f) a += cr[f] * ur[f];
      sdv[(size_t)(m0 + rl) * 12 + j] = a;
    }
  } else {
    int gl = m0 >> 11;
    int gi = c0 + gl;
    int tt = gi >> 1, ss = gi & 1;
    const float* xn = (ss ? xn2 : xn1) + (size_t)tt * NN;
    int nl0 = m0 & (NN - 1);
    if (t < 64) xnL[t] = xn[nl0 + t];
    __syncthreads();
    int d = t & 63, q = t >> 6;
    float a = 0.f;
    #pragma unroll
    for (int i = 0; i < 16; ++i) a += xnL[q * 16 + i] * CT[(q * 16 + i) * (BN + 1) + d];
    red[t] = a;
    __syncthreads();
    if (t < 64)
      atomicAdd(&seqv[tt * 128 + ss * 64 + t], red[t] + red[t + 64] + red[t + 128] + red[t + 192]);
  }
}

// ---------- GRU: parallel gi precompute ----------
__global__ __launch_bounds__(128)
void gi_kernel(const float* __restrict__ seq, const float* __restrict__ Wih,
               const float* __restrict__ bih, float* __restrict__ giAll) {
  int o = blockIdx.x * 128 + threadIdx.x;   // 48 blocks -> TS*96
  int tt = o / 96, j = o - tt * 96;
  const float4* wr = (const float4*)(Wih + (size_t)j * 128);
  const float4* xr = (const float4*)(seq + (size_t)tt * 128);
  float a = bih[j];
  #pragma unroll 8
  for (int k = 0; k < 32; ++k) {
    float4 w = wr[k], x = xr[k];
    a += w.x * x.x + w.y * x.y + w.z * x.z + w.w * x.w;
  }
  giAll[o] = a;
}

// ---------- GRU sequential + head (small, 1 block) ----------
__global__ __launch_bounds__(128)
void gru_seq_kernel(const float* __restrict__ giAll, const float* __restrict__ Whh,
                    const float* __restrict__ bhh, const float* __restrict__ Wc1,
                    const float* __restrict__ bc1, const float* __restrict__ Wc2,
                    const float* __restrict__ bc2, float* __restrict__ out) {
  __shared__ __align__(16) float WhhL[96 * 32];
  __shared__ __align__(16) float giL[TS * 96];
  __shared__ float rnnS[TS * 32];
  __shared__ float Wc1L[512], Wc2L[48], bc1L[16], bc2L[3], bhhL[96];
  __shared__ float ghs[96];
  __shared__ __align__(16) float hs[32];
  int t = threadIdx.x;
  for (int i = t; i < 96 * 32; i += 128) WhhL[i] = Whh[i];
  for (int i = t; i < TS * 96; i += 128) giL[i] = giAll[i];
  for (int i = t; i < 512; i += 128) Wc1L[i] = Wc1[i];
  if (t < 48) Wc2L[t] = Wc2[t];
  if (t < 96) bhhL[t] = bhh[t];
  if (t >= 96 && t < 112) bc1L[t - 96] = bc1[t - 96];
  if (t >= 112 && t < 115) bc2L[t - 112] = bc2[t - 112];
  if (t < 32) hs[t] = 0.f;
  __syncthreads();
  for (int tt = 0; tt < TS; ++tt) {
    if (t < 96) {
      const float4* wr = (const float4*)(WhhL + t * 32);
      const float4* hr = (const float4*)hs;
      float b = bhhL[t];
      #pragma unroll
      for (int k = 0; k < 8; ++k) {
        float4 w = wr[k], x = hr[k];
        b += w.x * x.x + w.y * x.y + w.z * x.z + w.w * x.w;
      }
      ghs[t] = b;
    }
    __syncthreads();
    if (t < 32) {
      const float* gi = giL + tt * 96;
      float r = sigm(gi[t] + ghs[t]);
      float z = sigm(gi[32 + t] + ghs[32 + t]);
      float nv = tanhf(gi[64 + t] + r * ghs[64 + t]);
      float h2 = (1.f - z) * nv + z * hs[t];
      hs[t] = h2;
      rnnS[tt * 32 + t] = h2;
    }
    __syncthreads();
  }
  for (int o = t; o < TS * 3; o += 128) {
    int tt = o / 3, c = o - tt * 3;
    float accv = bc2L[c];
    #pragma unroll
    for (int m = 0; m < 16; ++m) {
      float hv = bc1L[m];
      #pragma unroll
      for (int k = 0; k < 32; ++k) hv += rnnS[tt * 32 + k] * Wc1L[k * 16 + m];
      hv = fmaxf(hv, 0.f);
      accv += hv * Wc2L[m * 3 + c];
    }
    out[o] = accv;
  }
}

static inline size_t alignup(size_t x) { return (x + 255) & ~(size_t)255; }
static inline size_t maxsz(size_t a, size_t b) { return a > b ? a : b; }

extern "C" void kernel_launch(void* const* d_in, const int* in_sizes, int n_in,
                              void* d_out, int out_size, void* d_ws, size_t ws_size,
                              hipStream_t stream) {
  const float* x1  = (const float*)d_in[0];
  const float* x2  = (const float*)d_in[1];
  const int*   ei1 = (const int*)d_in[2];
  const int*   ei2 = (const int*)d_in[3];
  const float* ew1 = (const float*)d_in[4];
  const float* ew2 = (const float*)d_in[5];
  const float* xn1 = (const float*)d_in[6];
  const float* xn2 = (const float*)d_in[7];
  const float* Wih = (const float*)d_in[25];
  const float* Whh = (const float*)d_in[26];
  const float* bih = (const float*)d_in[27];
  const float* bhh = (const float*)d_in[28];
  const float* Wc1 = (const float*)d_in[29];
  const float* bc1 = (const float*)d_in[30];
  const float* Wc2 = (const float*)d_in[31];
  const float* bc2 = (const float*)d_in[32];
  float* out = (float*)d_out;

  const size_t uoffs[4] = {0, 24, 792, 1560};
  const size_t woffs[4] = {0, 3072, 101376, 150528};

  size_t off = 0;
  auto take = [&](size_t bytes) -> size_t { size_t o = off; off += alignup(bytes); return o; };
  size_t o_rowptr = take((size_t)NB * (NN + 1) * sizeof(int));
  size_t o_edges  = take((size_t)NB * NE * sizeof(int2));
  size_t o_uS     = take(1944 * sizeof(float));
  size_t o_uD     = take(1944 * sizeof(float));
  size_t o_bth    = take(175104 * sizeof(unsigned short));
  size_t o_btl    = take(175104 * sizeof(unsigned short));
  size_t o_seq    = take((size_t)TS * 128 * sizeof(float));
  size_t o_gi     = take((size_t)TS * 96 * sizeof(float));
  size_t o_sd0    = take((size_t)NB * NN * 12 * sizeof(float));   // layer-0 logits, all graphs
  size_t persistent = off;

  const size_t BKT_BYTES = (size_t)NB * 8 * BCAP * sizeof(int2);          // 48 MB
  const size_t BKT_NEED  = BKT_BYTES + 4096 + (size_t)NB * NN * sizeof(int);

  int G = 8;
  const int cand[3] = {32, 16, 8};
  for (int ci = 0; ci < 3; ++ci) {
    int g = cand[ci];
    size_t aggB = (size_t)g * NN * 768 * sizeof(unsigned int);
    size_t need = persistent
                + alignup((size_t)g * NN * 128 * sizeof(float))
                + 2 * alignup((size_t)g * NN * 12 * sizeof(float))
                + alignup(maxsz(aggB, BKT_NEED));
    if (need <= ws_size) { G = g; break; }
  }
  size_t aggB = (size_t)G * NN * 768 * sizeof(unsigned int);
  size_t o_h   = take((size_t)G * NN * 128 * sizeof(float));
  size_t o_sdA = take((size_t)G * NN * 12 * sizeof(float));
  size_t o_sdB = take((size_t)G * NN * 12 * sizeof(float));
  size_t o_agg = take(maxsz(aggB, BKT_NEED));
  int sw = ((G & 7) == 0) ? 1 : 0;

  char* ws = (char*)d_ws;
  int*   row_ptr = (int*)(ws + o_rowptr);
  int2*  edges   = (int2*)(ws + o_edges);
  float* uS   = (float*)(ws + o_uS);
  float* uD   = (float*)(ws + o_uD);
  unsigned short* bth = (unsigned short*)(ws + o_bth);
  unsigned short* btl = (unsigned short*)(ws + o_btl);
  float* seq   = (float*)(ws + o_seq);
  float* giAll = (float*)(ws + o_gi);
  float* sd0   = (float*)(ws + o_sd0);
  float* hbuf  = (float*)(ws + o_h);
  float* sdA   = (float*)(ws + o_sdA);
  float* sdB   = (float*)(ws + o_sdB);
  unsigned int* aggbuf = (unsigned int*)(ws + o_agg);
  // transient CSR scratch aliased onto aggbuf
  int2* bkt    = (int2*)(ws + o_agg);
  int*  bktCnt = (int*)(ws + o_agg + BKT_BYTES);
  int*  deg    = (int*)(ws + o_agg + BKT_BYTES + 4096);

  // ---- prep + CSR + sd0 + zero ----
  PrepArgs pa;
  for (int l = 0; l < 4; ++l) {
    pa.W[l]  = (const float*)d_in[9 + 4 * l];
    pa.aS[l] = (const float*)d_in[10 + 4 * l];
    pa.aD[l] = (const float*)d_in[11 + 4 * l];
  }
  prep_all_kernel<<<dim3(384, 4), 256, 0, stream>>>(pa, uS, uD, bth, btl);
  hipMemsetAsync(ws + o_agg + BKT_BYTES, 0, 4096 + (size_t)NB * NN * sizeof(int), stream);
  hipMemsetAsync(seq, 0, (size_t)TS * 128 * sizeof(float), stream);
  hist_part_kernel<<<NB * 8, 256, 0, stream>>>(ei1, ei2, deg);
  scan_kernel<<<NB, 256, 0, stream>>>(deg, row_ptr);
  bucketA_kernel<<<NB * 8, 256, 0, stream>>>(ei1, ei2, ew1, ew2, bktCnt, bkt);
  scatterB_kernel<<<NB * 8, 256, 0, stream>>>(bktCnt, bkt, row_ptr, edges);
  sd0_all_kernel<<<NB * NN / 256, 256, 0, stream>>>(x1, x2, uS, uD, sd0);

  // ---- chunked GAT pipeline (7 dispatches per chunk) ----
  for (int c0 = 0; c0 < NB; c0 += G) {
    int rows = G * NN;

    // layer 0 fused: agg(FIN=4, x direct)+GEMM(K=24,BN=128) -> hbuf, sd -> sdB
    gemm0f_kernel<<<rows / 64, 256, 0, stream>>>(
        x1, x2, sd0, row_ptr, edges, bth + woffs[0], btl + woffs[0],
        (const float*)d_in[12], hbuf, sw, uS + uoffs[1], uD + uoffs[1], sdB, c0);

    // layer 1: FIN=128 -> FOUT=128 (sd epilogue -> sdA)
    aggc_kernel<128, 4><<<rows / 32, 256, 0, stream>>>(hbuf, sdB, row_ptr, edges,
                                                       aggbuf, c0, sw);
    gemm_mfma_kernel<128, 2, 4, 2, 2, 1><<<rows / 64, 256, 0, stream>>>(
        aggbuf, bth + woffs[1], btl + woffs[1], (const float*)d_in[16], hbuf,
        768, 1, sw, uS + uoffs[2], uD + uoffs[2], sdA, nullptr, nullptr, nullptr, c0);

    // layer 2: FIN=128 -> FOUT=64 (sd epilogue -> sdB), h in-place stride 64
    aggc_kernel<128, 4><<<rows / 32, 256, 0, stream>>>(hbuf, sdA, row_ptr, edges,
                                                       aggbuf, c0, sw);
    gemm_mfma_kernel<64, 1, 4, 4, 1, 1><<<rows / 64, 256, 0, stream>>>(
        aggbuf, bth + woffs[2], btl + woffs[2], (const float*)d_in[20], hbuf,
        768, 1, sw, uS + uoffs[3], uD + uoffs[3], sdB, nullptr, nullptr, nullptr, c0);

    // layer 3: FIN=64 -> FOUT=64, readout epilogue (no C write)
    aggc_kernel<64, 2><<<rows / 64, 256, 0, stream>>>(hbuf, sdB, row_ptr, edges,
                                                      aggbuf, c0, sw);
    gemm_mfma_kernel<64, 1, 4, 4, 1, 2><<<rows / 64, 256, 0, stream>>>(
        aggbuf, bth + woffs[3], btl + woffs[3], (const float*)d_in[24], nullptr,
        384, 0, sw, nullptr, nullptr, nullptr, xn1, xn2, seq, c0);
  }

  // ---- GRU + head ----
  gi_kernel<<<48, 128, 0, stream>>>(seq, Wih, bih, giAll);
  gru_seq_kernel<<<1, 128, 0, stream>>>(giAll, Whh, bhh, Wc1, bc1, Wc2, bc2, out);
}